// Round 7
// baseline (105.710 us; speedup 1.0000x reference)
//
#include <hip/hip_runtime.h>

// DR splitting solver. BATCH=4096, N=96 (64 x + 32 s), M=48 (16 eq + 32 ineq).
// JF and Hessian are batch-independent => prox_g1 is an affine map y = P x + Bmat p.
//   S=(I+Q)^{-1}; T=S Jx^T; K2=Jx T+diag(0,I32); R2=K2^{-1}[T^T|E];
//   P=diag(S,I)-[T;E^T]R2; Bmat=[-P[:,:64] | R2^T]
// Iterate 10x: y=Px+c; x += clamp(2y-x,l,u)-y; out=y[:64].
//
// Round-6 lesson: re-striping prep to 1024 threads turned the "R2 cols>=64"
// grid-stride loop (1536 tasks) into a single-shot `if` -> rows 32..47 stale.
// Round-7 = round-6 + that loop restored. (1024-thr prep, 2x2 GJ tiles,
// 384-thr iter with 1 P-row/thread in registers.)

__device__ __forceinline__ float dot4f(float4 a, float4 b) {
  return a.x*b.x + a.y*b.y + a.z*b.z + a.w*b.w;
}
__device__ __forceinline__ void ld4(const float* p, float* d) {
  float4 v = *(const float4*)p;
  d[0] = v.x; d[1] = v.y; d[2] = v.z; d[3] = v.w;
}
__device__ __forceinline__ void st4(float* p, const float* s) {
  *(float4*)p = make_float4(s[0], s[1], s[2], s[3]);
}
__device__ __forceinline__ float fastrcp(float x) {
  float r = __builtin_amdgcn_rcpf(x);
  return r * (2.0f - x * r);     // 1 Newton step: ~1e-7 rel
}
// in-place 4x4 inverse by GJ, no pivoting (SPD principal blocks)
__device__ __forceinline__ void inv4(float D[4][4]) {
  #pragma unroll
  for (int p = 0; p < 4; ++p) {
    float pi = fastrcp(D[p][p]);
    D[p][p] = pi;
    #pragma unroll
    for (int q = 0; q < 4; ++q) if (q != p) D[p][q] *= pi;
    #pragma unroll
    for (int i = 0; i < 4; ++i) if (i != p) {
      float f = D[i][p];
      #pragma unroll
      for (int q = 0; q < 4; ++q) if (q != p) D[i][q] -= f * D[p][q];
      D[i][p] = -f * pi;
    }
  }
}

// one double-buffered block-GJ step on an n x n matrix, 2x2 tile per thread.
// thread (ig2, jg2) owns rows {2ig2, 2ig2+1} x cols {2jg2, 2jg2+1}.
__device__ __forceinline__ void gj2x2(const float* __restrict__ src,
                                      float* __restrict__ dst,
                                      int b, int ig2, int jg2, int stride) {
  float D[4][4];
  #pragma unroll
  for (int r = 0; r < 4; ++r) ld4(&src[(4*b + r)*stride + 4*b], D[r]);
  float C[2][4];
  ld4(&src[(2*ig2 + 0)*stride + 4*b], C[0]);
  ld4(&src[(2*ig2 + 1)*stride + 4*b], C[1]);
  float R[4][2];
  #pragma unroll
  for (int r = 0; r < 4; ++r) {
    float2 v = *(const float2*)&src[(4*b + r)*stride + 2*jg2];
    R[r][0] = v.x; R[r][1] = v.y;
  }
  float T2[2][2];
  #pragma unroll
  for (int r = 0; r < 2; ++r) {
    float2 v = *(const float2*)&src[(2*ig2 + r)*stride + 2*jg2];
    T2[r][0] = v.x; T2[r][1] = v.y;
  }
  inv4(D);
  const bool br = (ig2 >> 1) == b, bc = (jg2 >> 1) == b;
  const int ri = (ig2 & 1) * 2, ci = (jg2 & 1) * 2;
  float W[2][2];
  if (br) {
    if (bc) {
      W[0][0] = D[ri][ci];   W[0][1] = D[ri][ci+1];
      W[1][0] = D[ri+1][ci]; W[1][1] = D[ri+1][ci+1];
    } else {
      #pragma unroll
      for (int r = 0; r < 2; ++r)
        #pragma unroll
        for (int q = 0; q < 2; ++q) {
          float s = D[ri+r][0] * R[0][q];
          #pragma unroll
          for (int k = 1; k < 4; ++k) s += D[ri+r][k] * R[k][q];
          W[r][q] = s;
        }
    }
  } else {
    float E[2][4];
    #pragma unroll
    for (int r = 0; r < 2; ++r)
      #pragma unroll
      for (int k = 0; k < 4; ++k) {
        float s = C[r][0] * D[0][k];
        #pragma unroll
        for (int m = 1; m < 4; ++m) s += C[r][m] * D[m][k];
        E[r][k] = s;
      }
    if (bc) {
      W[0][0] = -E[0][ci]; W[0][1] = -E[0][ci+1];
      W[1][0] = -E[1][ci]; W[1][1] = -E[1][ci+1];
    } else {
      #pragma unroll
      for (int r = 0; r < 2; ++r)
        #pragma unroll
        for (int q = 0; q < 2; ++q) {
          float s = T2[r][q];
          #pragma unroll
          for (int k = 0; k < 4; ++k) s -= E[r][k] * R[k][q];
          W[r][q] = s;
        }
    }
  }
  *(float2*)&dst[(2*ig2 + 0)*stride + 2*jg2] = make_float2(W[0][0], W[0][1]);
  *(float2*)&dst[(2*ig2 + 1)*stride + 2*jg2] = make_float2(W[1][0], W[1][1]);
}

// ---------------------------------------------------------------- kernel A
__global__ __launch_bounds__(1024, 1) void prep_kernel(
    const float* __restrict__ Qg, const float* __restrict__ Ag,
    const float* __restrict__ Gg,
    float* __restrict__ Pg, float* __restrict__ Bg)
{
  // floats: 4352 + 4352 + 2496 + 4608 = 15808 = 63232 B
  __shared__ float sMa[64*68];   // M1 ping  -> S (after 16 steps)
  __shared__ float sMb[64*68];   // M1 pong  -> T (64x48, stride 48)
  __shared__ float sK [48*52];   // K2 ping  -> Ki
  __shared__ float sR2[48*96];   // Jx (s68) -> K2 pong (s52) -> R2 (s96)

#define SM_(i,j) sMa[(i)*68+(j)]
#define TT_(i,j) sMb[(i)*48+(j)]
#define SK_(i,j) sK[(i)*52+(j)]
#define JX_(a,k) sR2[(a)*68+(k)]

  const int tid = threadIdx.x;   // 0..1023

  // ---- stage Jx = [A;G] (48x64, stride 68) and M1 = Q + I
  {
    const float4* A4 = (const float4*)Ag;          // 256 quads
    const float4* G4 = (const float4*)Gg;          // 512 quads
    const float4* Q4 = (const float4*)Qg;          // 1024 quads
    if (tid < 256) {
      int a = tid >> 4, kc = tid & 15;
      st4(&JX_(a, kc*4), (const float*)&A4[tid]);
    }
    if (tid < 512) {
      int a = tid >> 4, kc = tid & 15;
      st4(&JX_(16 + a, kc*4), (const float*)&G4[tid]);
    }
    {
      int i = tid >> 4, kc = tid & 15;
      st4(&SM_(i, kc*4), (const float*)&Q4[tid]);
    }
  }
  __syncthreads();
  if (tid < 64) SM_(tid, tid) += 1.0f;
  __syncthreads();

  // ---- block-GJ 64 (dbuf, 1 barrier/step, 16 steps) -> S in sMa
  {
    const int ig2 = tid >> 5, jg2 = tid & 31;      // 32x32 tile grid
    #pragma unroll 1
    for (int p = 0; p < 8; ++p) {
      gj2x2(sMa, sMb, 2*p, ig2, jg2, 68);
      __syncthreads();
      gj2x2(sMb, sMa, 2*p + 1, ig2, jg2, 68);
      __syncthreads();
    }
  }

  // ---- T = S Jx^T : T[i][j] = sum_k S[i][k]*Jx[j][k]  (3 outputs/thread)
  #pragma unroll 1
  for (int t = tid; t < 64*48; t += 1024) {
    int i = t / 48, j = t - i*48;
    float acc = 0.0f;
    #pragma unroll 1
    for (int k = 0; k < 64; k += 4)
      acc += dot4f(*(const float4*)&SM_(i,k), *(const float4*)&JX_(j,k));
    TT_(i,j) = acc;
  }
  __syncthreads();

  // ---- K2 = Jx T + diag(0,I32)  (576 threads, 1 row x 4 cols)
  if (tid < 576) {
    int a = tid / 12, bq = tid - (tid / 12) * 12;
    int b0 = bq * 4;
    float acc[4] = {};
    #pragma unroll 1
    for (int k = 0; k < 64; ++k) {
      float jv = JX_(a, k);
      float4 tb = *(const float4*)&TT_(k, b0);
      acc[0] += jv*tb.x; acc[1] += jv*tb.y;
      acc[2] += jv*tb.z; acc[3] += jv*tb.w;
    }
    #pragma unroll
    for (int q = 0; q < 4; ++q) {
      int b = b0 + q;
      SK_(a, b) = acc[q] + ((a == b && a >= 16) ? 1.0f : 0.0f);
    }
  }
  __syncthreads();

  // ---- block-GJ 48 (dbuf; pong overlays dead Jx region) -> Ki in sK
  {
    float* KP = sR2;             // 48*52 = 2496 <= 4608
    const bool act = tid < 576;
    const int ig2 = tid / 24, jg2 = tid - (tid / 24) * 24;
    #pragma unroll 1
    for (int p = 0; p < 6; ++p) {
      if (act) gj2x2(sK, KP, 2*p, ig2, jg2, 52);
      __syncthreads();
      if (act) gj2x2(KP, sK, 2*p + 1, ig2, jg2, 52);
      __syncthreads();
    }
  }
  // KP / JX dead; sR2 region becomes R2 (stride 96).

  // ---- R2 cols<64: R2[k][c] = sum_m Ki[k][m]*T[c][m]  (3 outputs/thread)
  #pragma unroll 1
  for (int t = tid; t < 48*64; t += 1024) {
    int k = t >> 6, c = t & 63;
    float acc = 0.0f;
    #pragma unroll 1
    for (int m = 0; m < 48; m += 4)
      acc += dot4f(*(const float4*)&SK_(k,m), *(const float4*)&TT_(c,m));
    sR2[k*96 + c] = acc;
    Bg[c*112 + 64 + k] = acc;          // Bmat[:,64:] = R2^T
  }
  // ---- R2 cols>=64 (selection from Ki) -- 1536 tasks, MUST grid-stride
  #pragma unroll 1
  for (int t = tid; t < 48*32; t += 1024) {
    int k = t >> 5, j = t & 31;
    float v = SK_(k, 16 + j);
    sR2[k*96 + 64 + j] = v;
    Bg[(64 + j)*112 + 64 + k] = v;
  }
  __syncthreads();

  // ---- P heavy rows (i<64): P = S_diag - T*R2  (1 row x 4 cols, 1536 tasks)
  #pragma unroll 1
  for (int t = tid; t < 1536; t += 1024) {
    int i = t / 24, jq = t - (t / 24) * 24;
    int j0 = jq * 4;
    float acc[4];
    #pragma unroll
    for (int q = 0; q < 4; ++q)
      acc[q] = (j0 < 64) ? SM_(i, j0 + q) : 0.0f;
    #pragma unroll 1
    for (int m = 0; m < 48; m += 4) {
      float tv[4], rv[4][4];
      ld4(&TT_(i, m), tv);
      ld4(&sR2[(m+0)*96 + j0], rv[0]);
      ld4(&sR2[(m+1)*96 + j0], rv[1]);
      ld4(&sR2[(m+2)*96 + j0], rv[2]);
      ld4(&sR2[(m+3)*96 + j0], rv[3]);
      #pragma unroll
      for (int q = 0; q < 4; ++q)
        #pragma unroll
        for (int s = 0; s < 4; ++s)
          acc[q] -= tv[s] * rv[s][q];
    }
    #pragma unroll
    for (int q = 0; q < 4; ++q) {
      int j = j0 + q;
      float v = acc[q];
      Pg[i*96 + j] = v;
      if (j0 < 64) Bg[i*112 + j] = -v;     // Bmat[:,:64] = -P[:,:64]
    }
  }
  // ---- P rows >= 64: P[64+a][j] = (64+a==j) - R2[16+a][j]
  #pragma unroll 1
  for (int t = tid; t < 32*96; t += 1024) {
    int a = t / 96, j = t - (t / 96) * 96;
    float v = ((64 + a) == j ? 1.0f : 0.0f) - sR2[(16 + a)*96 + j];
    Pg[(64 + a)*96 + j] = v;
    if (j < 64) Bg[(64 + a)*112 + j] = -v;
  }
#undef SM_
#undef TT_
#undef SK_
#undef JX_
}

// ---------------------------------------------------------------- kernel B
#define EB 8   // elements per block; grid = 512 blocks x 384 threads

__global__ __launch_bounds__(384, 1) void iter_kernel(
    const float* __restrict__ xg, const float* __restrict__ pg,
    const float* __restrict__ Pg, const float* __restrict__ Bg,
    float* __restrict__ outg)
{
  // 4 groups x 96 rows: thread = (g, r). Thread owns P row r in registers
  // (24 float4 = 96 VGPR) for elements {2g, 2g+1}. LDS: x (static dbuf) + parms.
  __shared__ float sX[2][EB][100];
  __shared__ float sPar[EB][112];

  const int tid = threadIdx.x;          // 0..383
  const int gbase = blockIdx.x * EB;
  const int g = tid / 96;               // 0..3
  const int r = tid - 96 * g;           // 0..95
  const int e0 = 2 * g;

  // stage x (192 quads) and parms (224 quads)
  const float4* X4 = (const float4*)xg;
  if (tid < 192) {
    int e = tid / 24, kc = tid - (tid / 24) * 24;
    *(float4*)&sX[0][e][kc*4] = X4[gbase*24 + tid];
  }
  const float4* Par4 = (const float4*)pg;
  if (tid < 224) {
    int e = tid / 28, jc = tid - (tid / 28) * 28;
    *(float4*)&sPar[e][jc*4] = Par4[gbase*28 + tid];
  }

  // my P row -> registers (issued before the barrier; lands under c-phase)
  float4 pA[24];
  const float4* P4 = (const float4*)Pg;
  #pragma unroll
  for (int kq = 0; kq < 24; ++kq) pA[kq] = P4[r*24 + kq];

  __syncthreads();

  // c = Bmat(row r) @ parms(elems e0, e0+1), in registers
  float c0 = 0.f, c1 = 0.f;
  {
    const float4* B4 = (const float4*)Bg;
    #pragma unroll 1
    for (int jc = 0; jc < 28; ++jc) {
      float4 bm = B4[r*28 + jc];
      c0 += dot4f(bm, *(const float4*)&sPar[e0    ][jc*4]);
      c1 += dot4f(bm, *(const float4*)&sPar[e0 + 1][jc*4]);
    }
  }

  const float lo = (r < 64) ? -1000.0f : 0.0f;

  auto do_iter = [&](const float (*src)[100], float (*dst)[100], bool last) {
    // split accumulators: two independent 48-deep FMA chains per output
    float a0 = c0, a1 = c1, b0 = 0.f, b1 = 0.f;
    #pragma unroll
    for (int kq = 0; kq < 24; kq += 2) {
      float4 x0a = *(const float4*)&src[e0    ][kq*4];
      float4 x1a = *(const float4*)&src[e0 + 1][kq*4];
      float4 x0b = *(const float4*)&src[e0    ][kq*4 + 4];
      float4 x1b = *(const float4*)&src[e0 + 1][kq*4 + 4];
      a0 += dot4f(pA[kq],     x0a);  a1 += dot4f(pA[kq],     x1a);
      b0 += dot4f(pA[kq + 1], x0b);  b1 += dot4f(pA[kq + 1], x1b);
    }
    float y0 = a0 + b0, y1 = a1 + b1;
    if (!last) {
      float xo0 = src[e0    ][r];
      float xo1 = src[e0 + 1][r];
      float z0 = fminf(fmaxf(2.f*y0 - xo0, lo), 1000.f);
      float z1 = fminf(fmaxf(2.f*y1 - xo1, lo), 1000.f);
      dst[e0    ][r] = xo0 + z0 - y0;
      dst[e0 + 1][r] = xo1 + z1 - y1;
      __syncthreads();
    } else {
      if (r < 64) {
        outg[(gbase + e0    )*64 + r] = y0;
        outg[(gbase + e0 + 1)*64 + r] = y1;
      }
    }
  };

  do_iter(sX[0], sX[1], false);   // it 0
  do_iter(sX[1], sX[0], false);   // it 1
  do_iter(sX[0], sX[1], false);   // it 2
  do_iter(sX[1], sX[0], false);   // it 3
  do_iter(sX[0], sX[1], false);   // it 4
  do_iter(sX[1], sX[0], false);   // it 5
  do_iter(sX[0], sX[1], false);   // it 6
  do_iter(sX[1], sX[0], false);   // it 7
  do_iter(sX[0], sX[1], false);   // it 8
  do_iter(sX[1], sX[0], true);    // it 9 -> output
}

// ---------------------------------------------------------------- launch
extern "C" void kernel_launch(void* const* d_in, const int* in_sizes, int n_in,
                              void* d_out, int out_size, void* d_ws, size_t ws_size,
                              hipStream_t stream) {
  const float* x     = (const float*)d_in[0];   // (4096, 96)
  const float* parms = (const float*)d_in[1];   // (4096, 112)
  const float* Qg    = (const float*)d_in[2];   // (64, 64)
  const float* Ag    = (const float*)d_in[3];   // (16, 64)
  const float* Gg    = (const float*)d_in[4];   // (32, 64)
  float* out = (float*)d_out;                   // (4096, 64)

  float* ws  = (float*)d_ws;
  float* Pg  = ws;               // 96*96  = 9216
  float* Bg  = ws + 9216;        // 96*112 = 10752

  prep_kernel<<<1, 1024, 0, stream>>>(Qg, Ag, Gg, Pg, Bg);
  iter_kernel<<<4096 / EB, 384, 0, stream>>>(x, parms, Pg, Bg, out);
}